// Round 2
// baseline (615.591 us; speedup 1.0000x reference)
//
#include <hip/hip_runtime.h>
#include <hip/hip_bf16.h>

// Problem constants (fixed by the reference)
#define BB 8
#define CC 512
#define TT 4096
#define HH 8
#define DH 64
#define EPS 1e-6f

using bf16x8 = __attribute__((ext_vector_type(8))) short;
using s16x4  = __attribute__((ext_vector_type(4))) short;
using f32x4  = __attribute__((ext_vector_type(4))) float;

__device__ __forceinline__ short f2b(float f) {
  unsigned u = __float_as_uint(f);
  u += 0x7fffu + ((u >> 16) & 1u);   // round-to-nearest-even bf16
  return (short)(u >> 16);
}
__device__ __forceinline__ float b2f(short s) {
  unsigned u = ((unsigned)(unsigned short)s) << 16;
  return __uint_as_float(u);
}

// ---------------------------------------------------------------------------
// GEMM: Y[b][o][t] = sum_c W[o][c] * X[b][c][t] + bias[o]  (+ resid if fp32 out)
// 128x128 tile, BK=32, 4 waves, mfma_f32_16x16x32_bf16.
// LDS row stride 72 shorts (144B): 16B aligned; 2-way bank aliasing only (free).
// ---------------------------------------------------------------------------
template<bool IN_BF16, bool OUT_BF16>
__global__ __launch_bounds__(256) void gemm_conv(
    const float* __restrict__ W, const void* __restrict__ Xv,
    const float* __restrict__ bias, const float* __restrict__ resid,
    void* __restrict__ Yv)
{
  __shared__ short As[128][72];   // As[o][c]
  __shared__ short Bs[128][72];   // Bs[t][c]  (transposed x tile)
  const int tid = threadIdx.x;
  const int b  = blockIdx.z;
  const int m0 = blockIdx.y * 128;
  const int n0 = blockIdx.x * 128;

  f32x4 acc[4][4] = {};

  const int wid = tid >> 6, lane = tid & 63;
  const int wr = (wid >> 1) * 64, wc = (wid & 1) * 64;
  const int lr = lane & 15, lk8 = (lane >> 4) * 8;

  for (int k0 = 0; k0 < CC; k0 += 32) {
    // stage A: W tile 128x32 fp32 -> bf16
    {
      int r = tid >> 3, c4 = (tid & 7) * 4;
      #pragma unroll
      for (int it = 0; it < 4; ++it) {
        const float* s = W + (size_t)(m0 + r + it * 32) * CC + k0 + c4;
        float4 v = *(const float4*)s;
        s16x4 h = { f2b(v.x), f2b(v.y), f2b(v.z), f2b(v.w) };
        *(s16x4*)&As[r + it * 32][c4] = h;
      }
    }
    // stage B: x tile 32x128 -> Bs[t][c]
    {
      int t = tid & 127, cb = (tid >> 7) * 4;
      #pragma unroll
      for (int it = 0; it < 4; ++it) {
        int c = cb + it * 8;
        s16x4 h;
        if constexpr (IN_BF16) {
          const short* Xb = (const short*)Xv + (size_t)b * CC * TT;
          #pragma unroll
          for (int j = 0; j < 4; ++j)
            h[j] = Xb[(size_t)(k0 + c + j) * TT + n0 + t];
        } else {
          const float* Xb = (const float*)Xv + (size_t)b * CC * TT;
          #pragma unroll
          for (int j = 0; j < 4; ++j)
            h[j] = f2b(Xb[(size_t)(k0 + c + j) * TT + n0 + t]);
        }
        *(s16x4*)&Bs[t][c] = h;
      }
    }
    __syncthreads();
    bf16x8 af[4], bfr[4];
    #pragma unroll
    for (int m = 0; m < 4; ++m) af[m]  = *(const bf16x8*)&As[wr + m * 16 + lr][lk8];
    #pragma unroll
    for (int n = 0; n < 4; ++n) bfr[n] = *(const bf16x8*)&Bs[wc + n * 16 + lr][lk8];
    #pragma unroll
    for (int m = 0; m < 4; ++m)
      #pragma unroll
      for (int n = 0; n < 4; ++n)
        acc[m][n] = __builtin_amdgcn_mfma_f32_16x16x32_bf16(af[m], bfr[n], acc[m][n], 0, 0, 0);
    __syncthreads();
  }

  // epilogue: D[row=(lane>>4)*4+r][col=lane&15]
  const int lq4 = (lane >> 4) * 4;
  #pragma unroll
  for (int m = 0; m < 4; ++m) {
    #pragma unroll
    for (int r = 0; r < 4; ++r) {
      int o = m0 + wr + m * 16 + lq4 + r;
      float bv = bias[o];
      #pragma unroll
      for (int n = 0; n < 4; ++n) {
        int t = n0 + wc + n * 16 + lr;
        size_t idx = ((size_t)b * CC + o) * TT + t;
        float val = acc[m][n][r] + bv;
        if constexpr (OUT_BF16) {
          ((short*)Yv)[idx] = f2b(val);
        } else {
          ((float*)Yv)[idx] = val + resid[idx];
        }
      }
    }
  }
}

// ---------------------------------------------------------------------------
// q feature: RMSNorm over C -> elu+1 -> per-head softmax over 64 -> * 8^-0.5
// one thread per (b,t) column; in-place on bf16 Y.
// ---------------------------------------------------------------------------
__global__ __launch_bounds__(256) void feat_q(short* __restrict__ Y, const float* __restrict__ g)
{
  int b = blockIdx.y;
  int t = blockIdx.x * 256 + threadIdx.x;
  short* col = Y + (size_t)b * CC * TT + t;
  float ss = 0.f;
  for (int c = 0; c < CC; ++c) { float v = b2f(col[(size_t)c * TT]); ss += v * v; }
  float rn = rsqrtf(ss * (1.0f / CC) + EPS);
  #pragma unroll 1
  for (int h = 0; h < HH; ++h) {
    float vals[DH];
    float mx = -1e30f;
    #pragma unroll
    for (int j = 0; j < DH; ++j) {
      int c = h * DH + j;
      float x = b2f(col[(size_t)c * TT]) * rn * g[c];
      float f = x > 0.f ? x + 1.f : __expf(x);   // elu(x)+1
      vals[j] = f;
      mx = fmaxf(mx, f);
    }
    float s = 0.f;
    #pragma unroll
    for (int j = 0; j < DH; ++j) { float e = __expf(vals[j] - mx); vals[j] = e; s += e; }
    float inv = 0.35355339059327373f / s;  // 8^-0.5 / sum
    #pragma unroll
    for (int j = 0; j < DH; ++j) col[(size_t)(h * DH + j) * TT] = f2b(vals[j] * inv);
  }
}

// k feature: RMSNorm -> elu+1, in-place bf16 (time-softmax follows)
__global__ __launch_bounds__(256) void feat_k(short* __restrict__ Y, const float* __restrict__ g)
{
  int b = blockIdx.y;
  int t = blockIdx.x * 256 + threadIdx.x;
  short* col = Y + (size_t)b * CC * TT + t;
  float ss = 0.f;
  for (int c = 0; c < CC; ++c) { float v = b2f(col[(size_t)c * TT]); ss += v * v; }
  float rn = rsqrtf(ss * (1.0f / CC) + EPS);
  for (int c = 0; c < CC; ++c) {
    float x = b2f(col[(size_t)c * TT]) * rn * g[c];
    col[(size_t)c * TT] = f2b(x > 0.f ? x + 1.f : __expf(x));
  }
}

// v feature: RMSNorm -> elu+1 -> /64, in-place bf16
__global__ __launch_bounds__(256) void feat_v(short* __restrict__ Y, const float* __restrict__ g)
{
  int b = blockIdx.y;
  int t = blockIdx.x * 256 + threadIdx.x;
  short* col = Y + (size_t)b * CC * TT + t;
  float ss = 0.f;
  for (int c = 0; c < CC; ++c) { float v = b2f(col[(size_t)c * TT]); ss += v * v; }
  float rn = rsqrtf(ss * (1.0f / CC) + EPS);
  for (int c = 0; c < CC; ++c) {
    float x = b2f(col[(size_t)c * TT]) * rn * g[c];
    float f = x > 0.f ? x + 1.f : __expf(x);
    col[(size_t)c * TT] = f2b(f * (1.0f / DH));
  }
}

// k time-softmax with padding mask (mask true -> value -10000), bf16 in-place
__global__ __launch_bounds__(256) void softmax_k(short* __restrict__ Y,
                                                 const unsigned char* __restrict__ mask)
{
  int row = blockIdx.x;            // b*512 + c
  int b = row >> 9;
  short* p = Y + (size_t)row * TT;
  const unsigned char* m = mask + (size_t)b * TT;
  int tid = threadIdx.x;
  float v[16];
  float mx = -1e30f;
  #pragma unroll
  for (int s = 0; s < 16; ++s) {
    int t = tid + s * 256;
    float x = m[t] ? -10000.f : b2f(p[t]);
    v[s] = x; mx = fmaxf(mx, x);
  }
  __shared__ float red[4];
  #pragma unroll
  for (int off = 32; off; off >>= 1) mx = fmaxf(mx, __shfl_xor(mx, off));
  if ((tid & 63) == 0) red[tid >> 6] = mx;
  __syncthreads();
  mx = fmaxf(fmaxf(red[0], red[1]), fmaxf(red[2], red[3]));
  float sum = 0.f;
  #pragma unroll
  for (int s = 0; s < 16; ++s) { float e = __expf(v[s] - mx); v[s] = e; sum += e; }
  __syncthreads();
  #pragma unroll
  for (int off = 32; off; off >>= 1) sum += __shfl_xor(sum, off);
  if ((tid & 63) == 0) red[tid >> 6] = sum;
  __syncthreads();
  sum = red[0] + red[1] + red[2] + red[3];
  float inv = 1.f / sum;
  #pragma unroll
  for (int s = 0; s < 16; ++s) p[tid + s * 256] = f2b(v[s] * inv);
}

// ---------------------------------------------------------------------------
// ctx partials: ctx[bh][i][j] = sum_t k[bh][i][t] * v[bh][j][t]
// MFMA directly from global bf16; 8 chunks of 512 t; 4 waves, wave owns i-block.
// ---------------------------------------------------------------------------
__global__ __launch_bounds__(256) void ctx_mfma(const short* __restrict__ K,
                                                const short* __restrict__ V,
                                                float* __restrict__ P)
{
  int bh = blockIdx.y, chunk = blockIdx.x;
  int tid = threadIdx.x, wid = tid >> 6, lane = tid & 63;
  int lr = lane & 15, lk8 = (lane >> 4) * 8;
  const short* Kb = K + (size_t)bh * DH * TT + (size_t)chunk * 512;
  const short* Vb = V + (size_t)bh * DH * TT + (size_t)chunk * 512;
  f32x4 acc[4] = {};
  for (int t = 0; t < 512; t += 32) {
    bf16x8 a = *(const bf16x8*)&Kb[(size_t)(wid * 16 + lr) * TT + t + lk8];
    #pragma unroll
    for (int n = 0; n < 4; ++n) {
      bf16x8 bv = *(const bf16x8*)&Vb[(size_t)(n * 16 + lr) * TT + t + lk8];
      acc[n] = __builtin_amdgcn_mfma_f32_16x16x32_bf16(a, bv, acc[n], 0, 0, 0);
    }
  }
  float* pp = P + ((size_t)chunk * 64 + bh) * (DH * DH);
  int rq = (lane >> 4) * 4;
  #pragma unroll
  for (int n = 0; n < 4; ++n)
    #pragma unroll
    for (int r = 0; r < 4; ++r)
      pp[(wid * 16 + rq + r) * DH + n * 16 + lr] = acc[n][r];
}

__global__ __launch_bounds__(256) void ctx_reduce(const float* __restrict__ P, float* __restrict__ CTX)
{
  int i = blockIdx.x * 256 + threadIdx.x;    // < 64*4096
  float s = 0.f;
  #pragma unroll
  for (int c = 0; c < 8; ++c) s += P[(size_t)c * 64 * DH * DH + i];
  CTX[i] = s;
}

// out[bh][v][t] = sum_q q[bh][q][t] * ctx[bh][q][v]; ctx reads wave-uniform
__global__ __launch_bounds__(256) void attn_out(const short* __restrict__ Q,
                                                const float* __restrict__ CTX,
                                                short* __restrict__ O)
{
  int bh = blockIdx.y;
  int t = blockIdx.x * 256 + threadIdx.x;
  const short* qb = Q + (size_t)bh * DH * TT + t;
  const float* cb = CTX + (size_t)bh * DH * DH;
  float qv[DH];
  #pragma unroll
  for (int q = 0; q < DH; ++q) qv[q] = b2f(qb[(size_t)q * TT]);
  short* ob = O + (size_t)bh * DH * TT + t;
  #pragma unroll 1
  for (int v = 0; v < DH; ++v) {
    float s = 0.f;
    #pragma unroll
    for (int q = 0; q < DH; ++q) s += qv[q] * cb[q * DH + v];
    ob[(size_t)v * TT] = f2b(s);
  }
}

// final: rmsnorm(d_out, g_out) in place (d_out already has proj + residual)
__global__ __launch_bounds__(256) void final_rms(float* __restrict__ Y,
                                                 const float* __restrict__ g)
{
  int b = blockIdx.y;
  int t = blockIdx.x * 256 + threadIdx.x;
  float* col = Y + (size_t)b * CC * TT + t;
  float ss = 0.f;
  for (int c = 0; c < CC; ++c) { float v = col[(size_t)c * TT]; ss += v * v; }
  float rn = rsqrtf(ss * (1.0f / CC) + EPS);
  for (int c = 0; c < CC; ++c) col[(size_t)c * TT] = col[(size_t)c * TT] * rn * g[c];
}

// ---------------------------------------------------------------------------
extern "C" void kernel_launch(void* const* d_in, const int* in_sizes, int n_in,
                              void* d_out, int out_size, void* d_ws, size_t ws_size,
                              hipStream_t stream) {
  (void)in_sizes; (void)n_in; (void)out_size; (void)ws_size;
  const float* queries = (const float*)d_in[0];
  const float* keys    = (const float*)d_in[1];
  const float* values  = (const float*)d_in[2];
  const unsigned char* mask = (const unsigned char*)d_in[3];  // numpy bool = 1 byte
  const float* Wq = (const float*)d_in[4];
  const float* bq = (const float*)d_in[5];
  const float* gq = (const float*)d_in[6];
  const float* Wk = (const float*)d_in[7];
  const float* bk = (const float*)d_in[8];
  const float* gk = (const float*)d_in[9];
  const float* Wv = (const float*)d_in[10];
  const float* bv = (const float*)d_in[11];
  const float* gv = (const float*)d_in[12];
  const float* Wp = (const float*)d_in[13];
  const float* bp = (const float*)d_in[14];
  const float* g_out = (const float*)d_in[15];

  const size_t NCT = (size_t)BB * CC * TT;     // 16,777,216 elements
  // workspace layout (all bf16 except ctx slabs): ~105 MiB total
  short* qb16 = (short*)d_ws;                  // bf16 [B,C,T]  32 MiB
  short* kb16 = qb16 + NCT;                    // bf16 [B,C,T]  32 MiB (attn out reuses)
  short* vb16 = kb16 + NCT;                    // bf16 [B,C,T]  32 MiB
  float* ctxP = (float*)(vb16 + NCT);          // 8 x 64 x 64 x 64 fp32  8 MiB
  float* ctx  = ctxP + (size_t)8 * 64 * DH * DH;  // 1 MiB

  dim3 gGemm(TT / 128, CC / 128, BB);
  dim3 gCol(TT / 256, BB);

  gemm_conv<false, true><<<gGemm, 256, 0, stream>>>(Wq, queries, bq, nullptr, qb16);
  gemm_conv<false, true><<<gGemm, 256, 0, stream>>>(Wk, keys,    bk, nullptr, kb16);
  gemm_conv<false, true><<<gGemm, 256, 0, stream>>>(Wv, values,  bv, nullptr, vb16);

  feat_q<<<gCol, 256, 0, stream>>>(qb16, gq);
  feat_k<<<gCol, 256, 0, stream>>>(kb16, gk);
  feat_v<<<gCol, 256, 0, stream>>>(vb16, gv);

  softmax_k<<<dim3(BB * CC), 256, 0, stream>>>(kb16, mask);

  ctx_mfma<<<dim3(8, BB * HH), 256, 0, stream>>>(kb16, vb16, ctxP);
  ctx_reduce<<<dim3(64 * DH * DH / 256), 256, 0, stream>>>(ctxP, ctx);

  attn_out<<<dim3(TT / 256, BB * HH), 256, 0, stream>>>(qb16, ctx, kb16);  // kb16 now attn out

  gemm_conv<true, false><<<gGemm, 256, 0, stream>>>(Wp, kb16, bp, queries, d_out);  // + residual

  final_rms<<<gCol, 256, 0, stream>>>((float*)d_out, g_out);
}

// Round 3
// 458.843 us; speedup vs baseline: 1.3416x; 1.3416x over previous
//
#include <hip/hip_runtime.h>
#include <hip/hip_bf16.h>

// Problem constants (fixed by the reference)
#define BB 8
#define CC 512
#define TT 4096
#define HH 8
#define DH 64
#define EPS 1e-6f

using bf16x8 = __attribute__((ext_vector_type(8))) short;
using s16x4  = __attribute__((ext_vector_type(4))) short;
using f32x4  = __attribute__((ext_vector_type(4))) float;

__device__ __forceinline__ short f2b(float f) {
  unsigned u = __float_as_uint(f);
  u += 0x7fffu + ((u >> 16) & 1u);   // round-to-nearest-even bf16
  return (short)(u >> 16);
}
__device__ __forceinline__ float b2f(short s) {
  unsigned u = ((unsigned)(unsigned short)s) << 16;
  return __uint_as_float(u);
}
__device__ __forceinline__ unsigned pack2(short lo, short hi) {
  return ((unsigned)(unsigned short)lo) | (((unsigned)(unsigned short)hi) << 16);
}

// ---------------------------------------------------------------------------
// GEMM: Y[b][o][t] = sum_c W[o][c] * X[b][c][t] + bias[o]  (+ resid if fp32 out)
// 128x128 tile, BK=32, 4 waves, mfma_f32_16x16x32_bf16.
// ---------------------------------------------------------------------------
template<bool IN_BF16, bool OUT_BF16>
__global__ __launch_bounds__(256) void gemm_conv(
    const float* __restrict__ W, const void* __restrict__ Xv,
    const float* __restrict__ bias, const float* __restrict__ resid,
    void* __restrict__ Yv)
{
  __shared__ short As[128][72];   // As[o][c]
  __shared__ short Bs[128][72];   // Bs[t][c]  (transposed x tile)
  const int tid = threadIdx.x;
  const int b  = blockIdx.z;
  const int m0 = blockIdx.y * 128;
  const int n0 = blockIdx.x * 128;

  f32x4 acc[4][4] = {};

  const int wid = tid >> 6, lane = tid & 63;
  const int wr = (wid >> 1) * 64, wc = (wid & 1) * 64;
  const int lr = lane & 15, lk8 = (lane >> 4) * 8;

  for (int k0 = 0; k0 < CC; k0 += 32) {
    // stage A: W tile 128x32 fp32 -> bf16
    {
      int r = tid >> 3, c4 = (tid & 7) * 4;
      #pragma unroll
      for (int it = 0; it < 4; ++it) {
        const float* s = W + (size_t)(m0 + r + it * 32) * CC + k0 + c4;
        float4 v = *(const float4*)s;
        s16x4 h = { f2b(v.x), f2b(v.y), f2b(v.z), f2b(v.w) };
        *(s16x4*)&As[r + it * 32][c4] = h;
      }
    }
    // stage B: x tile 32x128 -> Bs[t][c]
    {
      int t = tid & 127, cb = (tid >> 7) * 4;
      #pragma unroll
      for (int it = 0; it < 4; ++it) {
        int c = cb + it * 8;
        s16x4 h;
        if constexpr (IN_BF16) {
          const short* Xb = (const short*)Xv + (size_t)b * CC * TT;
          #pragma unroll
          for (int j = 0; j < 4; ++j)
            h[j] = Xb[(size_t)(k0 + c + j) * TT + n0 + t];
        } else {
          const float* Xb = (const float*)Xv + (size_t)b * CC * TT;
          #pragma unroll
          for (int j = 0; j < 4; ++j)
            h[j] = f2b(Xb[(size_t)(k0 + c + j) * TT + n0 + t]);
        }
        *(s16x4*)&Bs[t][c] = h;
      }
    }
    __syncthreads();
    bf16x8 af[4], bfr[4];
    #pragma unroll
    for (int m = 0; m < 4; ++m) af[m]  = *(const bf16x8*)&As[wr + m * 16 + lr][lk8];
    #pragma unroll
    for (int n = 0; n < 4; ++n) bfr[n] = *(const bf16x8*)&Bs[wc + n * 16 + lr][lk8];
    #pragma unroll
    for (int m = 0; m < 4; ++m)
      #pragma unroll
      for (int n = 0; n < 4; ++n)
        acc[m][n] = __builtin_amdgcn_mfma_f32_16x16x32_bf16(af[m], bfr[n], acc[m][n], 0, 0, 0);
    __syncthreads();
  }

  // epilogue: D[row=(lane>>4)*4+r][col=lane&15]
  const int lq4 = (lane >> 4) * 4;
  #pragma unroll
  for (int m = 0; m < 4; ++m) {
    #pragma unroll
    for (int r = 0; r < 4; ++r) {
      int o = m0 + wr + m * 16 + lq4 + r;
      float bv = bias[o];
      #pragma unroll
      for (int n = 0; n < 4; ++n) {
        int t = n0 + wc + n * 16 + lr;
        size_t idx = ((size_t)b * CC + o) * TT + t;
        float val = acc[m][n][r] + bv;
        if constexpr (OUT_BF16) {
          ((short*)Yv)[idx] = f2b(val);
        } else {
          ((float*)Yv)[idx] = val + resid[idx];
        }
      }
    }
  }
}

// ---------------------------------------------------------------------------
// Column-wise feature kernels.
// Grid (T/64, B), 256 threads = 32 column-pairs x 8 channel-groups.
// Thread owns 2 adjacent t-columns and 64 channels (its group g = head for Q).
// MODE: 0=Q (norm->elu+1->head softmax->*8^-0.5), 1=K (norm->elu+1),
//       2=V (norm->elu+1->/64), 3=FINAL (fp32 in-place rmsnorm)
// ---------------------------------------------------------------------------
template<int MODE>
__global__ __launch_bounds__(256) void col_feat(void* __restrict__ Yv, const float* __restrict__ g)
{
  __shared__ float sred[8][64];
  const int b   = blockIdx.y;
  const int cp  = threadIdx.x & 31;          // column pair
  const int grp = threadIdx.x >> 5;          // channel group (= head for Q)
  const int t   = blockIdx.x * 64 + cp * 2;

  float fa[64], fb[64];
  float ss0 = 0.f, ss1 = 0.f;

  float* colf = nullptr; short* colh = nullptr;
  if constexpr (MODE == 3) {
    colf = (float*)Yv + ((size_t)b * CC + grp * 64) * TT + t;
    #pragma unroll
    for (int j = 0; j < 64; ++j) {
      float2 v = *(const float2*)(colf + (size_t)j * TT);
      fa[j] = v.x; fb[j] = v.y;
      ss0 += v.x * v.x; ss1 += v.y * v.y;
    }
  } else {
    colh = (short*)Yv + ((size_t)b * CC + grp * 64) * TT + t;
    #pragma unroll
    for (int j = 0; j < 64; ++j) {
      unsigned u = *(const unsigned*)(colh + (size_t)j * TT);
      float x = __uint_as_float(u << 16);
      float y = __uint_as_float(u & 0xffff0000u);
      fa[j] = x; fb[j] = y;
      ss0 += x * x; ss1 += y * y;
    }
  }

  const int c2 = cp * 2;
  sred[grp][c2] = ss0; sred[grp][c2 + 1] = ss1;
  __syncthreads();
  float s0 = 0.f, s1 = 0.f;
  #pragma unroll
  for (int k = 0; k < 8; ++k) { s0 += sred[k][c2]; s1 += sred[k][c2 + 1]; }
  const float rn0 = rsqrtf(s0 * (1.0f / CC) + EPS);
  const float rn1 = rsqrtf(s1 * (1.0f / CC) + EPS);

  if constexpr (MODE == 3) {
    #pragma unroll
    for (int j = 0; j < 64; ++j) {
      float gc = g[grp * 64 + j];
      float2 o; o.x = fa[j] * rn0 * gc; o.y = fb[j] * rn1 * gc;
      *(float2*)(colf + (size_t)j * TT) = o;
    }
  } else if constexpr (MODE == 1 || MODE == 2) {
    const float mul = (MODE == 2) ? (1.0f / DH) : 1.0f;
    #pragma unroll
    for (int j = 0; j < 64; ++j) {
      float gc = g[grp * 64 + j];
      float x = fa[j] * rn0 * gc;
      float y = fb[j] * rn1 * gc;
      float u = (x > 0.f ? x + 1.f : __expf(x)) * mul;
      float v = (y > 0.f ? y + 1.f : __expf(y)) * mul;
      *(unsigned*)(colh + (size_t)j * TT) = pack2(f2b(u), f2b(v));
    }
  } else { // Q: elu+1 then softmax over the 64 channels of this head, no max
           // subtraction needed: |x| <= sqrt(C) => f <= ~23.6, exp(f) <= 2e10
    float sum0 = 0.f, sum1 = 0.f;
    #pragma unroll
    for (int j = 0; j < 64; ++j) {
      float gc = g[grp * 64 + j];
      float x = fa[j] * rn0 * gc;
      float y = fb[j] * rn1 * gc;
      float u = x > 0.f ? x + 1.f : __expf(x);
      float v = y > 0.f ? y + 1.f : __expf(y);
      u = __expf(u); v = __expf(v);
      fa[j] = u; fb[j] = v;
      sum0 += u; sum1 += v;
    }
    const float i0 = 0.35355339059327373f / sum0;  // 8^-0.5 / sum
    const float i1 = 0.35355339059327373f / sum1;
    #pragma unroll
    for (int j = 0; j < 64; ++j)
      *(unsigned*)(colh + (size_t)j * TT) = pack2(f2b(fa[j] * i0), f2b(fb[j] * i1));
  }
}

// k time-softmax with padding mask (mask true -> value -10000), bf16 in-place
__global__ __launch_bounds__(256) void softmax_k(short* __restrict__ Y,
                                                 const unsigned char* __restrict__ mask)
{
  int row = blockIdx.x;            // b*512 + c
  int b = row >> 9;
  short* p = Y + (size_t)row * TT;
  const unsigned char* m = mask + (size_t)b * TT;
  int tid = threadIdx.x;
  float v[16];
  float mx = -1e30f;
  #pragma unroll
  for (int s = 0; s < 16; ++s) {
    int t = tid + s * 256;
    float x = m[t] ? -10000.f : b2f(p[t]);
    v[s] = x; mx = fmaxf(mx, x);
  }
  __shared__ float red[4];
  #pragma unroll
  for (int off = 32; off; off >>= 1) mx = fmaxf(mx, __shfl_xor(mx, off));
  if ((tid & 63) == 0) red[tid >> 6] = mx;
  __syncthreads();
  mx = fmaxf(fmaxf(red[0], red[1]), fmaxf(red[2], red[3]));
  float sum = 0.f;
  #pragma unroll
  for (int s = 0; s < 16; ++s) { float e = __expf(v[s] - mx); v[s] = e; sum += e; }
  __syncthreads();
  #pragma unroll
  for (int off = 32; off; off >>= 1) sum += __shfl_xor(sum, off);
  if ((tid & 63) == 0) red[tid >> 6] = sum;
  __syncthreads();
  sum = red[0] + red[1] + red[2] + red[3];
  float inv = 1.f / sum;
  #pragma unroll
  for (int s = 0; s < 16; ++s) p[tid + s * 256] = f2b(v[s] * inv);
}

// ---------------------------------------------------------------------------
// ctx partials: ctx[bh][i][j] = sum_t k[bh][i][t] * v[bh][j][t]
// MFMA directly from global bf16; 8 chunks of 512 t; 4 waves, wave owns i-block.
// ---------------------------------------------------------------------------
__global__ __launch_bounds__(256) void ctx_mfma(const short* __restrict__ K,
                                                const short* __restrict__ V,
                                                float* __restrict__ P)
{
  int bh = blockIdx.y, chunk = blockIdx.x;
  int tid = threadIdx.x, wid = tid >> 6, lane = tid & 63;
  int lr = lane & 15, lk8 = (lane >> 4) * 8;
  const short* Kb = K + (size_t)bh * DH * TT + (size_t)chunk * 512;
  const short* Vb = V + (size_t)bh * DH * TT + (size_t)chunk * 512;
  f32x4 acc[4] = {};
  for (int t = 0; t < 512; t += 32) {
    bf16x8 a = *(const bf16x8*)&Kb[(size_t)(wid * 16 + lr) * TT + t + lk8];
    #pragma unroll
    for (int n = 0; n < 4; ++n) {
      bf16x8 bv = *(const bf16x8*)&Vb[(size_t)(n * 16 + lr) * TT + t + lk8];
      acc[n] = __builtin_amdgcn_mfma_f32_16x16x32_bf16(a, bv, acc[n], 0, 0, 0);
    }
  }
  float* pp = P + ((size_t)chunk * 64 + bh) * (DH * DH);
  int rq = (lane >> 4) * 4;
  #pragma unroll
  for (int n = 0; n < 4; ++n)
    #pragma unroll
    for (int r = 0; r < 4; ++r)
      pp[(wid * 16 + rq + r) * DH + n * 16 + lr] = acc[n][r];
}

__global__ __launch_bounds__(256) void ctx_reduce(const float* __restrict__ P, float* __restrict__ CTX)
{
  int i = blockIdx.x * 256 + threadIdx.x;    // < 64*4096
  float s = 0.f;
  #pragma unroll
  for (int c = 0; c < 8; ++c) s += P[(size_t)c * 64 * DH * DH + i];
  CTX[i] = s;
}

// out[bh][v][t] = sum_q q[bh][q][t] * ctx[bh][q][v]; ctx reads wave-uniform
__global__ __launch_bounds__(256) void attn_out(const short* __restrict__ Q,
                                                const float* __restrict__ CTX,
                                                short* __restrict__ O)
{
  int bh = blockIdx.y;
  int t = blockIdx.x * 256 + threadIdx.x;
  const short* qb = Q + (size_t)bh * DH * TT + t;
  const float* cb = CTX + (size_t)bh * DH * DH;
  float qv[DH];
  #pragma unroll
  for (int q = 0; q < DH; ++q) qv[q] = b2f(qb[(size_t)q * TT]);
  short* ob = O + (size_t)bh * DH * TT + t;
  #pragma unroll 1
  for (int v = 0; v < DH; ++v) {
    float s = 0.f;
    #pragma unroll
    for (int q = 0; q < DH; ++q) s += qv[q] * cb[q * DH + v];
    ob[(size_t)v * TT] = f2b(s);
  }
}

// ---------------------------------------------------------------------------
extern "C" void kernel_launch(void* const* d_in, const int* in_sizes, int n_in,
                              void* d_out, int out_size, void* d_ws, size_t ws_size,
                              hipStream_t stream) {
  (void)in_sizes; (void)n_in; (void)out_size; (void)ws_size;
  const float* queries = (const float*)d_in[0];
  const float* keys    = (const float*)d_in[1];
  const float* values  = (const float*)d_in[2];
  const unsigned char* mask = (const unsigned char*)d_in[3];  // numpy bool = 1 byte
  const float* Wq = (const float*)d_in[4];
  const float* bq = (const float*)d_in[5];
  const float* gq = (const float*)d_in[6];
  const float* Wk = (const float*)d_in[7];
  const float* bk = (const float*)d_in[8];
  const float* gk = (const float*)d_in[9];
  const float* Wv = (const float*)d_in[10];
  const float* bv = (const float*)d_in[11];
  const float* gv = (const float*)d_in[12];
  const float* Wp = (const float*)d_in[13];
  const float* bp = (const float*)d_in[14];
  const float* g_out = (const float*)d_in[15];

  const size_t NCT = (size_t)BB * CC * TT;     // 16,777,216 elements
  short* qb16 = (short*)d_ws;                  // bf16 [B,C,T]  32 MiB
  short* kb16 = qb16 + NCT;                    // bf16 [B,C,T]  32 MiB (attn out reuses)
  short* vb16 = kb16 + NCT;                    // bf16 [B,C,T]  32 MiB
  float* ctxP = (float*)(vb16 + NCT);          // 8 x 64 x 64 x 64 fp32  8 MiB
  float* ctx  = ctxP + (size_t)8 * 64 * DH * DH;  // 1 MiB

  dim3 gGemm(TT / 128, CC / 128, BB);
  dim3 gCol(TT / 64, BB);

  gemm_conv<false, true><<<gGemm, 256, 0, stream>>>(Wq, queries, bq, nullptr, qb16);
  gemm_conv<false, true><<<gGemm, 256, 0, stream>>>(Wk, keys,    bk, nullptr, kb16);
  gemm_conv<false, true><<<gGemm, 256, 0, stream>>>(Wv, values,  bv, nullptr, vb16);

  col_feat<0><<<gCol, 256, 0, stream>>>(qb16, gq);
  col_feat<1><<<gCol, 256, 0, stream>>>(kb16, gk);
  col_feat<2><<<gCol, 256, 0, stream>>>(vb16, gv);

  softmax_k<<<dim3(BB * CC), 256, 0, stream>>>(kb16, mask);

  ctx_mfma<<<dim3(8, BB * HH), 256, 0, stream>>>(kb16, vb16, ctxP);
  ctx_reduce<<<dim3(64 * DH * DH / 256), 256, 0, stream>>>(ctxP, ctx);

  attn_out<<<dim3(TT / 256, BB * HH), 256, 0, stream>>>(qb16, ctx, kb16);  // kb16 now attn out

  gemm_conv<true, false><<<gGemm, 256, 0, stream>>>(Wp, kb16, bp, queries, d_out);  // + residual

  col_feat<3><<<gCol, 256, 0, stream>>>(d_out, g_out);
}

// Round 4
// 401.734 us; speedup vs baseline: 1.5323x; 1.1422x over previous
//
#include <hip/hip_runtime.h>
#include <hip/hip_bf16.h>

// Problem constants (fixed by the reference)
#define BB 8
#define CC 512
#define TT 4096
#define HH 8
#define DH 64
#define EPS 1e-6f

using bf16x8 = __attribute__((ext_vector_type(8))) short;
using s16x4  = __attribute__((ext_vector_type(4))) short;
using f32x4  = __attribute__((ext_vector_type(4))) float;

__device__ __forceinline__ short f2b(float f) {
  unsigned u = __float_as_uint(f);
  u += 0x7fffu + ((u >> 16) & 1u);   // round-to-nearest-even bf16
  return (short)(u >> 16);
}
__device__ __forceinline__ float b2f(short s) {
  unsigned u = ((unsigned)(unsigned short)s) << 16;
  return __uint_as_float(u);
}
__device__ __forceinline__ unsigned pack2(short lo, short hi) {
  return ((unsigned)(unsigned short)lo) | (((unsigned)(unsigned short)hi) << 16);
}

// ---------------------------------------------------------------------------
// GEMM: Y[b][o][t] = sum_c W[o][c] * X[b][c][t] + bias[o]  (+ resid if fp32 out)
// 128x128 tile, BK=32, 4 waves, mfma_f32_16x16x32_bf16.
// ---------------------------------------------------------------------------
template<bool IN_BF16, bool OUT_BF16>
__global__ __launch_bounds__(256) void gemm_conv(
    const float* __restrict__ W, const void* __restrict__ Xv,
    const float* __restrict__ bias, const float* __restrict__ resid,
    void* __restrict__ Yv)
{
  __shared__ short As[128][72];   // As[o][c]
  __shared__ short Bs[128][72];   // Bs[t][c]  (transposed x tile)
  const int tid = threadIdx.x;
  const int b  = blockIdx.z;
  const int m0 = blockIdx.y * 128;
  const int n0 = blockIdx.x * 128;

  f32x4 acc[4][4] = {};

  const int wid = tid >> 6, lane = tid & 63;
  const int wr = (wid >> 1) * 64, wc = (wid & 1) * 64;
  const int lr = lane & 15, lk8 = (lane >> 4) * 8;

  for (int k0 = 0; k0 < CC; k0 += 32) {
    // stage A: W tile 128x32 fp32 -> bf16
    {
      int r = tid >> 3, c4 = (tid & 7) * 4;
      #pragma unroll
      for (int it = 0; it < 4; ++it) {
        const float* s = W + (size_t)(m0 + r + it * 32) * CC + k0 + c4;
        float4 v = *(const float4*)s;
        s16x4 h = { f2b(v.x), f2b(v.y), f2b(v.z), f2b(v.w) };
        *(s16x4*)&As[r + it * 32][c4] = h;
      }
    }
    // stage B: x tile 32x128 -> Bs[t][c]
    {
      int t = tid & 127, cb = (tid >> 7) * 4;
      #pragma unroll
      for (int it = 0; it < 4; ++it) {
        int c = cb + it * 8;
        s16x4 h;
        if constexpr (IN_BF16) {
          const short* Xb = (const short*)Xv + (size_t)b * CC * TT;
          #pragma unroll
          for (int j = 0; j < 4; ++j)
            h[j] = Xb[(size_t)(k0 + c + j) * TT + n0 + t];
        } else {
          const float* Xb = (const float*)Xv + (size_t)b * CC * TT;
          #pragma unroll
          for (int j = 0; j < 4; ++j)
            h[j] = f2b(Xb[(size_t)(k0 + c + j) * TT + n0 + t]);
        }
        *(s16x4*)&Bs[t][c] = h;
      }
    }
    __syncthreads();
    bf16x8 af[4], bfr[4];
    #pragma unroll
    for (int m = 0; m < 4; ++m) af[m]  = *(const bf16x8*)&As[wr + m * 16 + lr][lk8];
    #pragma unroll
    for (int n = 0; n < 4; ++n) bfr[n] = *(const bf16x8*)&Bs[wc + n * 16 + lr][lk8];
    #pragma unroll
    for (int m = 0; m < 4; ++m)
      #pragma unroll
      for (int n = 0; n < 4; ++n)
        acc[m][n] = __builtin_amdgcn_mfma_f32_16x16x32_bf16(af[m], bfr[n], acc[m][n], 0, 0, 0);
    __syncthreads();
  }

  // epilogue: D[row=(lane>>4)*4+r][col=lane&15]
  const int lq4 = (lane >> 4) * 4;
  #pragma unroll
  for (int m = 0; m < 4; ++m) {
    #pragma unroll
    for (int r = 0; r < 4; ++r) {
      int o = m0 + wr + m * 16 + lq4 + r;
      float bv = bias[o];
      #pragma unroll
      for (int n = 0; n < 4; ++n) {
        int t = n0 + wc + n * 16 + lr;
        size_t idx = ((size_t)b * CC + o) * TT + t;
        float val = acc[m][n][r] + bv;
        if constexpr (OUT_BF16) {
          ((short*)Yv)[idx] = f2b(val);
        } else {
          ((float*)Yv)[idx] = val + resid[idx];
        }
      }
    }
  }
}

// ---------------------------------------------------------------------------
// Column-wise feature kernels.
// Grid (T/64, B), 256 threads = 32 column-pairs x 8 channel-groups.
// MODE: 0=Q (norm->elu+1->head softmax->*8^-0.5), 1=K (norm->elu+1),
//       2=V (norm->elu+1->/64), 3=FINAL (fp32 in-place rmsnorm)
// ---------------------------------------------------------------------------
template<int MODE>
__global__ __launch_bounds__(256) void col_feat(void* __restrict__ Yv, const float* __restrict__ g)
{
  __shared__ float sred[8][64];
  const int b   = blockIdx.y;
  const int cp  = threadIdx.x & 31;          // column pair
  const int grp = threadIdx.x >> 5;          // channel group (= head for Q)
  const int t   = blockIdx.x * 64 + cp * 2;

  float fa[64], fb[64];
  float ss0 = 0.f, ss1 = 0.f;

  float* colf = nullptr; short* colh = nullptr;
  if constexpr (MODE == 3) {
    colf = (float*)Yv + ((size_t)b * CC + grp * 64) * TT + t;
    #pragma unroll
    for (int j = 0; j < 64; ++j) {
      float2 v = *(const float2*)(colf + (size_t)j * TT);
      fa[j] = v.x; fb[j] = v.y;
      ss0 += v.x * v.x; ss1 += v.y * v.y;
    }
  } else {
    colh = (short*)Yv + ((size_t)b * CC + grp * 64) * TT + t;
    #pragma unroll
    for (int j = 0; j < 64; ++j) {
      unsigned u = *(const unsigned*)(colh + (size_t)j * TT);
      float x = __uint_as_float(u << 16);
      float y = __uint_as_float(u & 0xffff0000u);
      fa[j] = x; fb[j] = y;
      ss0 += x * x; ss1 += y * y;
    }
  }

  const int c2 = cp * 2;
  sred[grp][c2] = ss0; sred[grp][c2 + 1] = ss1;
  __syncthreads();
  float s0 = 0.f, s1 = 0.f;
  #pragma unroll
  for (int k = 0; k < 8; ++k) { s0 += sred[k][c2]; s1 += sred[k][c2 + 1]; }
  const float rn0 = rsqrtf(s0 * (1.0f / CC) + EPS);
  const float rn1 = rsqrtf(s1 * (1.0f / CC) + EPS);

  if constexpr (MODE == 3) {
    #pragma unroll
    for (int j = 0; j < 64; ++j) {
      float gc = g[grp * 64 + j];
      float2 o; o.x = fa[j] * rn0 * gc; o.y = fb[j] * rn1 * gc;
      *(float2*)(colf + (size_t)j * TT) = o;
    }
  } else if constexpr (MODE == 1 || MODE == 2) {
    const float mul = (MODE == 2) ? (1.0f / DH) : 1.0f;
    #pragma unroll
    for (int j = 0; j < 64; ++j) {
      float gc = g[grp * 64 + j];
      float x = fa[j] * rn0 * gc;
      float y = fb[j] * rn1 * gc;
      float u = (x > 0.f ? x + 1.f : __expf(x)) * mul;
      float v = (y > 0.f ? y + 1.f : __expf(y)) * mul;
      *(unsigned*)(colh + (size_t)j * TT) = pack2(f2b(u), f2b(v));
    }
  } else { // Q: elu+1 then softmax over the 64 channels of this head
    float sum0 = 0.f, sum1 = 0.f;
    #pragma unroll
    for (int j = 0; j < 64; ++j) {
      float gc = g[grp * 64 + j];
      float x = fa[j] * rn0 * gc;
      float y = fb[j] * rn1 * gc;
      float u = x > 0.f ? x + 1.f : __expf(x);
      float v = y > 0.f ? y + 1.f : __expf(y);
      u = __expf(u); v = __expf(v);
      fa[j] = u; fb[j] = v;
      sum0 += u; sum1 += v;
    }
    const float i0 = 0.35355339059327373f / sum0;  // 8^-0.5 / sum
    const float i1 = 0.35355339059327373f / sum1;
    #pragma unroll
    for (int j = 0; j < 64; ++j)
      *(unsigned*)(colh + (size_t)j * TT) = pack2(f2b(fa[j] * i0), f2b(fb[j] * i1));
  }
}

// k time-softmax with padding mask (mask true -> value -10000), bf16 in-place
__global__ __launch_bounds__(256) void softmax_k(short* __restrict__ Y,
                                                 const unsigned char* __restrict__ mask)
{
  int row = blockIdx.x;            // b*512 + c
  int b = row >> 9;
  short* p = Y + (size_t)row * TT;
  const unsigned char* m = mask + (size_t)b * TT;
  int tid = threadIdx.x;
  float v[16];
  float mx = -1e30f;
  #pragma unroll
  for (int s = 0; s < 16; ++s) {
    int t = tid + s * 256;
    float x = m[t] ? -10000.f : b2f(p[t]);
    v[s] = x; mx = fmaxf(mx, x);
  }
  __shared__ float red[4];
  #pragma unroll
  for (int off = 32; off; off >>= 1) mx = fmaxf(mx, __shfl_xor(mx, off));
  if ((tid & 63) == 0) red[tid >> 6] = mx;
  __syncthreads();
  mx = fmaxf(fmaxf(red[0], red[1]), fmaxf(red[2], red[3]));
  float sum = 0.f;
  #pragma unroll
  for (int s = 0; s < 16; ++s) { float e = __expf(v[s] - mx); v[s] = e; sum += e; }
  __syncthreads();
  #pragma unroll
  for (int off = 32; off; off >>= 1) sum += __shfl_xor(sum, off);
  if ((tid & 63) == 0) red[tid >> 6] = sum;
  __syncthreads();
  sum = red[0] + red[1] + red[2] + red[3];
  float inv = 1.f / sum;
  #pragma unroll
  for (int s = 0; s < 16; ++s) p[tid + s * 256] = f2b(v[s] * inv);
}

// ---------------------------------------------------------------------------
// ctx partials: ctxP[chunk][bh][i=q][j=v] = sum_t k[bh][i][t] * v[bh][j][t]
// ---------------------------------------------------------------------------
__global__ __launch_bounds__(256) void ctx_mfma(const short* __restrict__ K,
                                                const short* __restrict__ V,
                                                float* __restrict__ P)
{
  int bh = blockIdx.y, chunk = blockIdx.x;
  int tid = threadIdx.x, wid = tid >> 6, lane = tid & 63;
  int lr = lane & 15, lk8 = (lane >> 4) * 8;
  const short* Kb = K + (size_t)bh * DH * TT + (size_t)chunk * 512;
  const short* Vb = V + (size_t)bh * DH * TT + (size_t)chunk * 512;
  f32x4 acc[4] = {};
  for (int t = 0; t < 512; t += 32) {
    bf16x8 a = *(const bf16x8*)&Kb[(size_t)(wid * 16 + lr) * TT + t + lk8];
    #pragma unroll
    for (int n = 0; n < 4; ++n) {
      bf16x8 bv = *(const bf16x8*)&Vb[(size_t)(n * 16 + lr) * TT + t + lk8];
      acc[n] = __builtin_amdgcn_mfma_f32_16x16x32_bf16(a, bv, acc[n], 0, 0, 0);
    }
  }
  float* pp = P + ((size_t)chunk * 64 + bh) * (DH * DH);
  int rq = (lane >> 4) * 4;
  #pragma unroll
  for (int n = 0; n < 4; ++n)
    #pragma unroll
    for (int r = 0; r < 4; ++r)
      pp[(wid * 16 + rq + r) * DH + n * 16 + lr] = acc[n][r];
}

// reduce chunk partials and emit TRANSPOSED bf16 ctx: CT[bh][v][q]
__global__ __launch_bounds__(256) void ctx_reduce(const float* __restrict__ P, short* __restrict__ CT)
{
  int i = blockIdx.x * 256 + threadIdx.x;    // (bh, q, v), v fastest
  float s = 0.f;
  #pragma unroll
  for (int c = 0; c < 8; ++c) s += P[(size_t)c * 64 * DH * DH + i];
  int bh = i >> 12, rem = i & 4095, q = rem >> 6, v = rem & 63;
  CT[((size_t)bh << 12) + v * 64 + q] = f2b(s);
}

// ---------------------------------------------------------------------------
// attn out via MFMA: out[bh][v][t] = sum_q CT[bh][v][q] * qfeat[bh][q][t]
// Per block: full M=64 (v), N=256 t-cols, K=64 (q). 4 waves, 32 MFMA each.
// ---------------------------------------------------------------------------
__global__ __launch_bounds__(256) void attn_gemm(const short* __restrict__ CT,
                                                 const short* __restrict__ Q,
                                                 short* __restrict__ O)
{
  __shared__ short As[64][72];    // ctx^T [v][q]
  __shared__ short Bs[256][72];   // q tile [t][q]
  const int bh = blockIdx.y;
  const int t0 = blockIdx.x * 256;
  const int tid = threadIdx.x;

  // stage A: 4096 bf16, 16 consecutive per thread (2x16B vec loads)
  {
    const short* src = CT + ((size_t)bh << 12) + tid * 16;
    int r = tid >> 2, c = (tid & 3) * 16;
    bf16x8 v0 = *(const bf16x8*)(src);
    bf16x8 v1 = *(const bf16x8*)(src + 8);
    *(bf16x8*)&As[r][c] = v0;
    *(bf16x8*)&As[r][c + 8] = v1;
  }
  // stage B: thread owns column t0+tid, gathers 64 q-channels
  {
    const short* qb = Q + (size_t)bh * DH * TT + t0 + tid;
    #pragma unroll
    for (int q4 = 0; q4 < 64; q4 += 4) {
      s16x4 h;
      #pragma unroll
      for (int j = 0; j < 4; ++j) h[j] = qb[(size_t)(q4 + j) * TT];
      *(s16x4*)&Bs[tid][q4] = h;
    }
  }
  __syncthreads();

  const int wid = tid >> 6, lane = tid & 63;
  const int wc = wid * 64;
  const int lr = lane & 15, lk8 = (lane >> 4) * 8;
  f32x4 acc[4][4] = {};
  #pragma unroll
  for (int ks = 0; ks < 2; ++ks) {
    bf16x8 af[4], bfr[4];
    #pragma unroll
    for (int m = 0; m < 4; ++m) af[m] = *(const bf16x8*)&As[m * 16 + lr][ks * 32 + lk8];
    #pragma unroll
    for (int n = 0; n < 4; ++n) bfr[n] = *(const bf16x8*)&Bs[wc + n * 16 + lr][ks * 32 + lk8];
    #pragma unroll
    for (int m = 0; m < 4; ++m)
      #pragma unroll
      for (int n = 0; n < 4; ++n)
        acc[m][n] = __builtin_amdgcn_mfma_f32_16x16x32_bf16(af[m], bfr[n], acc[m][n], 0, 0, 0);
  }

  const int lq4 = (lane >> 4) * 4;
  short* ob = O + (size_t)bh * DH * TT;
  #pragma unroll
  for (int m = 0; m < 4; ++m)
    #pragma unroll
    for (int r = 0; r < 4; ++r) {
      int v = m * 16 + lq4 + r;
      #pragma unroll
      for (int n = 0; n < 4; ++n) {
        int t = t0 + wc + n * 16 + lr;
        ob[(size_t)v * TT + t] = f2b(acc[m][n][r]);
      }
    }
}

// ---------------------------------------------------------------------------
extern "C" void kernel_launch(void* const* d_in, const int* in_sizes, int n_in,
                              void* d_out, int out_size, void* d_ws, size_t ws_size,
                              hipStream_t stream) {
  (void)in_sizes; (void)n_in; (void)out_size; (void)ws_size;
  const float* queries = (const float*)d_in[0];
  const float* keys    = (const float*)d_in[1];
  const float* values  = (const float*)d_in[2];
  const unsigned char* mask = (const unsigned char*)d_in[3];  // numpy bool = 1 byte
  const float* Wq = (const float*)d_in[4];
  const float* bq = (const float*)d_in[5];
  const float* gq = (const float*)d_in[6];
  const float* Wk = (const float*)d_in[7];
  const float* bk = (const float*)d_in[8];
  const float* gk = (const float*)d_in[9];
  const float* Wv = (const float*)d_in[10];
  const float* bv = (const float*)d_in[11];
  const float* gv = (const float*)d_in[12];
  const float* Wp = (const float*)d_in[13];
  const float* bp = (const float*)d_in[14];
  const float* g_out = (const float*)d_in[15];

  const size_t NCT = (size_t)BB * CC * TT;     // 16,777,216 elements
  short* qb16 = (short*)d_ws;                  // bf16 [B,C,T]  32 MiB
  short* kb16 = qb16 + NCT;                    // bf16 [B,C,T]  32 MiB (attn out reuses)
  short* vb16 = kb16 + NCT;                    // bf16 [B,C,T]  32 MiB
  float* ctxP = (float*)(vb16 + NCT);          // 8 x 64 x 64 x 64 fp32  8 MiB
  short* ctxT = (short*)(ctxP + (size_t)8 * 64 * DH * DH);  // bf16 [bh][v][q] 512 KiB

  dim3 gGemm(TT / 128, CC / 128, BB);
  dim3 gCol(TT / 64, BB);

  gemm_conv<false, true><<<gGemm, 256, 0, stream>>>(Wq, queries, bq, nullptr, qb16);
  gemm_conv<false, true><<<gGemm, 256, 0, stream>>>(Wk, keys,    bk, nullptr, kb16);
  gemm_conv<false, true><<<gGemm, 256, 0, stream>>>(Wv, values,  bv, nullptr, vb16);

  col_feat<0><<<gCol, 256, 0, stream>>>(qb16, gq);
  col_feat<1><<<gCol, 256, 0, stream>>>(kb16, gk);
  col_feat<2><<<gCol, 256, 0, stream>>>(vb16, gv);

  softmax_k<<<dim3(BB * CC), 256, 0, stream>>>(kb16, mask);

  ctx_mfma<<<dim3(8, BB * HH), 256, 0, stream>>>(kb16, vb16, ctxP);
  ctx_reduce<<<dim3(64 * DH * DH / 256), 256, 0, stream>>>(ctxP, ctxT);

  attn_gemm<<<dim3(TT / 256, BB * HH), 256, 0, stream>>>(ctxT, qb16, kb16);  // kb16 now attn out

  gemm_conv<true, false><<<gGemm, 256, 0, stream>>>(Wp, kb16, bp, queries, d_out);  // + residual

  col_feat<3><<<gCol, 256, 0, stream>>>(d_out, g_out);
}

// Round 5
// 385.950 us; speedup vs baseline: 1.5950x; 1.0409x over previous
//
#include <hip/hip_runtime.h>
#include <hip/hip_bf16.h>

// Problem constants (fixed by the reference)
#define BB 8
#define CC 512
#define TT 4096
#define HH 8
#define DH 64
#define EPS 1e-6f

using bf16x8 = __attribute__((ext_vector_type(8))) short;
using s16x4  = __attribute__((ext_vector_type(4))) short;
using f32x4  = __attribute__((ext_vector_type(4))) float;

__device__ __forceinline__ short f2b(float f) {
  unsigned u = __float_as_uint(f);
  u += 0x7fffu + ((u >> 16) & 1u);   // round-to-nearest-even bf16
  return (short)(u >> 16);
}
__device__ __forceinline__ float b2f(short s) {
  unsigned u = ((unsigned)(unsigned short)s) << 16;
  return __uint_as_float(u);
}
__device__ __forceinline__ unsigned pack2(short lo, short hi) {
  return ((unsigned)(unsigned short)lo) | (((unsigned)(unsigned short)hi) << 16);
}

// W fp32 [o][c] -> bf16 [o][c] (no transpose; K=c already contiguous)
__global__ __launch_bounds__(256) void conv_w(const float* __restrict__ src,
                                              short* __restrict__ dst)
{
  int i8 = (blockIdx.x * 256 + threadIdx.x) * 8;
  float4 a = *(const float4*)(src + i8);
  float4 b = *(const float4*)(src + i8 + 4);
  bf16x8 h = { f2b(a.x), f2b(a.y), f2b(a.z), f2b(a.w),
               f2b(b.x), f2b(b.y), f2b(b.z), f2b(b.w) };
  *(bf16x8*)(dst + i8) = h;
}

// ---------------------------------------------------------------------------
// GEMM v2: Y[b][o][t] = sum_c W[o][c] * X[b][c][t] + bias[o]  (+resid if fp32)
// Full-M column block: tile [512 o][64 t], BK=32, 512 threads (8 waves).
// W pre-converted bf16, restaged per K-step from L2 with XOR-swizzled chunks.
// X staged once per element (coalesced row reads, padded-stride LDS).
// ---------------------------------------------------------------------------
template<bool IN_BF16, bool OUT_BF16>
__global__ __launch_bounds__(512, 4) void gemm_conv2(
    const short* __restrict__ Wb, const void* __restrict__ Xv,
    const float* __restrict__ bias, const float* __restrict__ resid,
    void* __restrict__ Yv)
{
  __shared__ short As[512 * 32];   // W tile [512 o][32 c], chunk-swizzled
  __shared__ short Bs[64 * 40];    // X tile [64 t][32 c], stride 40 (80B, 16B-aligned)

  const int tid = threadIdx.x;
  const int b   = blockIdx.y;
  const int t0  = blockIdx.x * 64;

  const int w    = tid >> 6, lane = tid & 63;
  const int lr   = lane & 15, g = lane >> 4;
  const int wrow = tid >> 2,  wcb = tid & 3;     // W staging: row 0..127 (+s*128), chunk 0..3
  const int xc   = tid >> 4;                     // X staging: c 0..31
  const int xt4  = (tid & 15) * 4;               // t offset 0..60

  f32x4 acc[4][4] = {};

  for (int k0 = 0; k0 < CC; k0 += 32) {
    // stage W: 512x32 bf16, coalesced 16B loads, swizzled LDS chunk
    #pragma unroll
    for (int s = 0; s < 4; ++s) {
      int row = s * 128 + wrow;
      bf16x8 wv = *(const bf16x8*)(Wb + (size_t)row * CC + k0 + wcb * 8);
      *(bf16x8*)&As[row * 32 + ((wcb ^ (row & 3)) * 8)] = wv;
    }
    // stage X: [32 c][64 t] -> Bs[t][c] (transpose in LDS, once per element)
    if constexpr (IN_BF16) {
      const short* Xb = (const short*)Xv + (size_t)b * CC * TT;
      s16x4 xv = *(const s16x4*)(Xb + (size_t)(k0 + xc) * TT + t0 + xt4);
      #pragma unroll
      for (int j = 0; j < 4; ++j) Bs[(xt4 + j) * 40 + xc] = xv[j];
    } else {
      const float* Xb = (const float*)Xv + (size_t)b * CC * TT;
      float4 xf = *(const float4*)(Xb + (size_t)(k0 + xc) * TT + t0 + xt4);
      Bs[(xt4 + 0) * 40 + xc] = f2b(xf.x);
      Bs[(xt4 + 1) * 40 + xc] = f2b(xf.y);
      Bs[(xt4 + 2) * 40 + xc] = f2b(xf.z);
      Bs[(xt4 + 3) * 40 + xc] = f2b(xf.w);
    }
    __syncthreads();

    // fragments + MFMA: wave w owns o in [w*64, w*64+64), all 64 t
    bf16x8 af[4];
    #pragma unroll
    for (int m = 0; m < 4; ++m) {
      int o = w * 64 + m * 16 + lr;
      af[m] = *(const bf16x8*)&As[o * 32 + ((g ^ (o & 3)) * 8)];
    }
    #pragma unroll
    for (int n = 0; n < 4; ++n) {
      int t = n * 16 + lr;
      bf16x8 bf = *(const bf16x8*)&Bs[t * 40 + g * 8];
      #pragma unroll
      for (int m = 0; m < 4; ++m)
        acc[m][n] = __builtin_amdgcn_mfma_f32_16x16x32_bf16(af[m], bf, acc[m][n], 0, 0, 0);
    }
    __syncthreads();
  }

  // epilogue: D row = o (= (lane>>4)*4 + r within 16-tile), col = t (= lane&15)
  const int lq4 = (lane >> 4) * 4;
  #pragma unroll
  for (int m = 0; m < 4; ++m) {
    #pragma unroll
    for (int r = 0; r < 4; ++r) {
      int o = w * 64 + m * 16 + lq4 + r;
      float bv = bias[o];
      #pragma unroll
      for (int n = 0; n < 4; ++n) {
        int t = t0 + n * 16 + lr;
        size_t idx = ((size_t)b * CC + o) * TT + t;
        float val = acc[m][n][r] + bv;
        if constexpr (OUT_BF16) {
          ((short*)Yv)[idx] = f2b(val);
        } else {
          ((float*)Yv)[idx] = val + resid[idx];
        }
      }
    }
  }
}

// ---------------------------------------------------------------------------
// Column-wise feature kernels (unchanged from round 4).
// MODE: 0=Q (norm->elu+1->head softmax->*8^-0.5), 1=K (norm->elu+1),
//       2=V (norm->elu+1->/64), 3=FINAL (fp32 in-place rmsnorm)
// ---------------------------------------------------------------------------
template<int MODE>
__global__ __launch_bounds__(256) void col_feat(void* __restrict__ Yv, const float* __restrict__ g)
{
  __shared__ float sred[8][64];
  const int b   = blockIdx.y;
  const int cp  = threadIdx.x & 31;          // column pair
  const int grp = threadIdx.x >> 5;          // channel group (= head for Q)
  const int t   = blockIdx.x * 64 + cp * 2;

  float fa[64], fb[64];
  float ss0 = 0.f, ss1 = 0.f;

  float* colf = nullptr; short* colh = nullptr;
  if constexpr (MODE == 3) {
    colf = (float*)Yv + ((size_t)b * CC + grp * 64) * TT + t;
    #pragma unroll
    for (int j = 0; j < 64; ++j) {
      float2 v = *(const float2*)(colf + (size_t)j * TT);
      fa[j] = v.x; fb[j] = v.y;
      ss0 += v.x * v.x; ss1 += v.y * v.y;
    }
  } else {
    colh = (short*)Yv + ((size_t)b * CC + grp * 64) * TT + t;
    #pragma unroll
    for (int j = 0; j < 64; ++j) {
      unsigned u = *(const unsigned*)(colh + (size_t)j * TT);
      float x = __uint_as_float(u << 16);
      float y = __uint_as_float(u & 0xffff0000u);
      fa[j] = x; fb[j] = y;
      ss0 += x * x; ss1 += y * y;
    }
  }

  const int c2 = cp * 2;
  sred[grp][c2] = ss0; sred[grp][c2 + 1] = ss1;
  __syncthreads();
  float s0 = 0.f, s1 = 0.f;
  #pragma unroll
  for (int k = 0; k < 8; ++k) { s0 += sred[k][c2]; s1 += sred[k][c2 + 1]; }
  const float rn0 = rsqrtf(s0 * (1.0f / CC) + EPS);
  const float rn1 = rsqrtf(s1 * (1.0f / CC) + EPS);

  if constexpr (MODE == 3) {
    #pragma unroll
    for (int j = 0; j < 64; ++j) {
      float gc = g[grp * 64 + j];
      float2 o; o.x = fa[j] * rn0 * gc; o.y = fb[j] * rn1 * gc;
      *(float2*)(colf + (size_t)j * TT) = o;
    }
  } else if constexpr (MODE == 1 || MODE == 2) {
    const float mul = (MODE == 2) ? (1.0f / DH) : 1.0f;
    #pragma unroll
    for (int j = 0; j < 64; ++j) {
      float gc = g[grp * 64 + j];
      float x = fa[j] * rn0 * gc;
      float y = fb[j] * rn1 * gc;
      float u = (x > 0.f ? x + 1.f : __expf(x)) * mul;
      float v = (y > 0.f ? y + 1.f : __expf(y)) * mul;
      *(unsigned*)(colh + (size_t)j * TT) = pack2(f2b(u), f2b(v));
    }
  } else { // Q: elu+1 then softmax over the 64 channels of this head
    float sum0 = 0.f, sum1 = 0.f;
    #pragma unroll
    for (int j = 0; j < 64; ++j) {
      float gc = g[grp * 64 + j];
      float x = fa[j] * rn0 * gc;
      float y = fb[j] * rn1 * gc;
      float u = x > 0.f ? x + 1.f : __expf(x);
      float v = y > 0.f ? y + 1.f : __expf(y);
      u = __expf(u); v = __expf(v);
      fa[j] = u; fb[j] = v;
      sum0 += u; sum1 += v;
    }
    const float i0 = 0.35355339059327373f / sum0;  // 8^-0.5 / sum
    const float i1 = 0.35355339059327373f / sum1;
    #pragma unroll
    for (int j = 0; j < 64; ++j)
      *(unsigned*)(colh + (size_t)j * TT) = pack2(f2b(fa[j] * i0), f2b(fb[j] * i1));
  }
}

// k time-softmax with padding mask (mask true -> value -10000), bf16 in-place
__global__ __launch_bounds__(256) void softmax_k(short* __restrict__ Y,
                                                 const unsigned char* __restrict__ mask)
{
  int row = blockIdx.x;            // b*512 + c
  int b = row >> 9;
  short* p = Y + (size_t)row * TT;
  const unsigned char* m = mask + (size_t)b * TT;
  int tid = threadIdx.x;
  float v[16];
  float mx = -1e30f;
  #pragma unroll
  for (int s = 0; s < 16; ++s) {
    int t = tid + s * 256;
    float x = m[t] ? -10000.f : b2f(p[t]);
    v[s] = x; mx = fmaxf(mx, x);
  }
  __shared__ float red[4];
  #pragma unroll
  for (int off = 32; off; off >>= 1) mx = fmaxf(mx, __shfl_xor(mx, off));
  if ((tid & 63) == 0) red[tid >> 6] = mx;
  __syncthreads();
  mx = fmaxf(fmaxf(red[0], red[1]), fmaxf(red[2], red[3]));
  float sum = 0.f;
  #pragma unroll
  for (int s = 0; s < 16; ++s) { float e = __expf(v[s] - mx); v[s] = e; sum += e; }
  __syncthreads();
  #pragma unroll
  for (int off = 32; off; off >>= 1) sum += __shfl_xor(sum, off);
  if ((tid & 63) == 0) red[tid >> 6] = sum;
  __syncthreads();
  sum = red[0] + red[1] + red[2] + red[3];
  float inv = 1.f / sum;
  #pragma unroll
  for (int s = 0; s < 16; ++s) p[tid + s * 256] = f2b(v[s] * inv);
}

// ---------------------------------------------------------------------------
// ctx partials: ctxP[chunk][bh][i=q][j=v] = sum_t k[bh][i][t] * v[bh][j][t]
// ---------------------------------------------------------------------------
__global__ __launch_bounds__(256) void ctx_mfma(const short* __restrict__ K,
                                                const short* __restrict__ V,
                                                float* __restrict__ P)
{
  int bh = blockIdx.y, chunk = blockIdx.x;
  int tid = threadIdx.x, wid = tid >> 6, lane = tid & 63;
  int lr = lane & 15, lk8 = (lane >> 4) * 8;
  const short* Kb = K + (size_t)bh * DH * TT + (size_t)chunk * 512;
  const short* Vb = V + (size_t)bh * DH * TT + (size_t)chunk * 512;
  f32x4 acc[4] = {};
  for (int t = 0; t < 512; t += 32) {
    bf16x8 a = *(const bf16x8*)&Kb[(size_t)(wid * 16 + lr) * TT + t + lk8];
    #pragma unroll
    for (int n = 0; n < 4; ++n) {
      bf16x8 bv = *(const bf16x8*)&Vb[(size_t)(n * 16 + lr) * TT + t + lk8];
      acc[n] = __builtin_amdgcn_mfma_f32_16x16x32_bf16(a, bv, acc[n], 0, 0, 0);
    }
  }
  float* pp = P + ((size_t)chunk * 64 + bh) * (DH * DH);
  int rq = (lane >> 4) * 4;
  #pragma unroll
  for (int n = 0; n < 4; ++n)
    #pragma unroll
    for (int r = 0; r < 4; ++r)
      pp[(wid * 16 + rq + r) * DH + n * 16 + lr] = acc[n][r];
}

// reduce chunk partials and emit TRANSPOSED bf16 ctx: CT[bh][v][q]
__global__ __launch_bounds__(256) void ctx_reduce(const float* __restrict__ P, short* __restrict__ CT)
{
  int i = blockIdx.x * 256 + threadIdx.x;    // (bh, q, v), v fastest
  float s = 0.f;
  #pragma unroll
  for (int c = 0; c < 8; ++c) s += P[(size_t)c * 64 * DH * DH + i];
  int bh = i >> 12, rem = i & 4095, q = rem >> 6, v = rem & 63;
  CT[((size_t)bh << 12) + v * 64 + q] = f2b(s);
}

// ---------------------------------------------------------------------------
// attn out via MFMA: out[bh][v][t] = sum_q CT[bh][v][q] * qfeat[bh][q][t]
// ---------------------------------------------------------------------------
__global__ __launch_bounds__(256) void attn_gemm(const short* __restrict__ CT,
                                                 const short* __restrict__ Q,
                                                 short* __restrict__ O)
{
  __shared__ short As[64][72];    // ctx^T [v][q]
  __shared__ short Bs[256][72];   // q tile [t][q]
  const int bh = blockIdx.y;
  const int t0 = blockIdx.x * 256;
  const int tid = threadIdx.x;

  // stage A: 4096 bf16, 16 consecutive per thread (2x16B vec loads)
  {
    const short* src = CT + ((size_t)bh << 12) + tid * 16;
    int r = tid >> 2, c = (tid & 3) * 16;
    bf16x8 v0 = *(const bf16x8*)(src);
    bf16x8 v1 = *(const bf16x8*)(src + 8);
    *(bf16x8*)&As[r][c] = v0;
    *(bf16x8*)&As[r][c + 8] = v1;
  }
  // stage B: thread owns column t0+tid, gathers 64 q-channels
  {
    const short* qb = Q + (size_t)bh * DH * TT + t0 + tid;
    #pragma unroll
    for (int q4 = 0; q4 < 64; q4 += 4) {
      s16x4 h;
      #pragma unroll
      for (int j = 0; j < 4; ++j) h[j] = qb[(size_t)(q4 + j) * TT];
      *(s16x4*)&Bs[tid][q4] = h;
    }
  }
  __syncthreads();

  const int wid = tid >> 6, lane = tid & 63;
  const int wc = wid * 64;
  const int lr = lane & 15, lk8 = (lane >> 4) * 8;
  f32x4 acc[4][4] = {};
  #pragma unroll
  for (int ks = 0; ks < 2; ++ks) {
    bf16x8 af[4], bfr[4];
    #pragma unroll
    for (int m = 0; m < 4; ++m) af[m] = *(const bf16x8*)&As[m * 16 + lr][ks * 32 + lk8];
    #pragma unroll
    for (int n = 0; n < 4; ++n) bfr[n] = *(const bf16x8*)&Bs[wc + n * 16 + lr][ks * 32 + lk8];
    #pragma unroll
    for (int m = 0; m < 4; ++m)
      #pragma unroll
      for (int n = 0; n < 4; ++n)
        acc[m][n] = __builtin_amdgcn_mfma_f32_16x16x32_bf16(af[m], bfr[n], acc[m][n], 0, 0, 0);
  }

  const int lq4 = (lane >> 4) * 4;
  short* ob = O + (size_t)bh * DH * TT;
  #pragma unroll
  for (int m = 0; m < 4; ++m)
    #pragma unroll
    for (int r = 0; r < 4; ++r) {
      int v = m * 16 + lq4 + r;
      #pragma unroll
      for (int n = 0; n < 4; ++n) {
        int t = t0 + wc + n * 16 + lr;
        ob[(size_t)v * TT + t] = f2b(acc[m][n][r]);
      }
    }
}

// ---------------------------------------------------------------------------
extern "C" void kernel_launch(void* const* d_in, const int* in_sizes, int n_in,
                              void* d_out, int out_size, void* d_ws, size_t ws_size,
                              hipStream_t stream) {
  (void)in_sizes; (void)n_in; (void)out_size; (void)ws_size;
  const float* queries = (const float*)d_in[0];
  const float* keys    = (const float*)d_in[1];
  const float* values  = (const float*)d_in[2];
  const unsigned char* mask = (const unsigned char*)d_in[3];  // numpy bool = 1 byte
  const float* Wq = (const float*)d_in[4];
  const float* bq = (const float*)d_in[5];
  const float* gq = (const float*)d_in[6];
  const float* Wk = (const float*)d_in[7];
  const float* bk = (const float*)d_in[8];
  const float* gk = (const float*)d_in[9];
  const float* Wv = (const float*)d_in[10];
  const float* bv = (const float*)d_in[11];
  const float* gv = (const float*)d_in[12];
  const float* Wp = (const float*)d_in[13];
  const float* bp = (const float*)d_in[14];
  const float* g_out = (const float*)d_in[15];

  const size_t NCT = (size_t)BB * CC * TT;     // 16,777,216 elements
  short* qb16 = (short*)d_ws;                  // bf16 [B,C,T]  32 MiB
  short* kb16 = qb16 + NCT;                    // bf16 [B,C,T]  32 MiB (attn out reuses)
  short* vb16 = kb16 + NCT;                    // bf16 [B,C,T]  32 MiB
  float* ctxP = (float*)(vb16 + NCT);          // 8 x 64 x 64 x 64 fp32  8 MiB
  short* ctxT = (short*)(ctxP + (size_t)8 * 64 * DH * DH);  // bf16 [bh][v][q] 512 KiB
  short* wqb  = ctxT + (size_t)64 * DH * DH;   // 4 x 512x512 bf16 = 2 MiB
  short* wkb  = wqb + (size_t)CC * CC;
  short* wvb  = wkb + (size_t)CC * CC;
  short* wpb  = wvb + (size_t)CC * CC;

  dim3 gGemm(TT / 64, BB);
  dim3 gCol(TT / 64, BB);

  conv_w<<<dim3(CC * CC / 2048), 256, 0, stream>>>(Wq, wqb);
  conv_w<<<dim3(CC * CC / 2048), 256, 0, stream>>>(Wk, wkb);
  conv_w<<<dim3(CC * CC / 2048), 256, 0, stream>>>(Wv, wvb);
  conv_w<<<dim3(CC * CC / 2048), 256, 0, stream>>>(Wp, wpb);

  gemm_conv2<false, true><<<gGemm, 512, 0, stream>>>(wqb, queries, bq, nullptr, qb16);
  gemm_conv2<false, true><<<gGemm, 512, 0, stream>>>(wkb, keys,    bk, nullptr, kb16);
  gemm_conv2<false, true><<<gGemm, 512, 0, stream>>>(wvb, values,  bv, nullptr, vb16);

  col_feat<0><<<gCol, 256, 0, stream>>>(qb16, gq);
  col_feat<1><<<gCol, 256, 0, stream>>>(kb16, gk);
  col_feat<2><<<gCol, 256, 0, stream>>>(vb16, gv);

  softmax_k<<<dim3(BB * CC), 256, 0, stream>>>(kb16, mask);

  ctx_mfma<<<dim3(8, BB * HH), 256, 0, stream>>>(kb16, vb16, ctxP);
  ctx_reduce<<<dim3(64 * DH * DH / 256), 256, 0, stream>>>(ctxP, ctxT);

  attn_gemm<<<dim3(TT / 256, BB * HH), 256, 0, stream>>>(ctxT, qb16, kb16);  // kb16 now attn out

  gemm_conv2<true, false><<<gGemm, 512, 0, stream>>>(wpb, kb16, bp, queries, d_out);  // + residual

  col_feat<3><<<gCol, 256, 0, stream>>>(d_out, g_out);
}